// Round 15
// baseline (55.559 us; speedup 1.0000x reference)
//
#include <hip/hip_runtime.h>

#define B_ 32
#define T_ 4096
#define D_ 256
#define A_ 128

typedef __attribute__((ext_vector_type(8))) short bf16x8;
typedef __attribute__((ext_vector_type(4))) float f32x4;
typedef __attribute__((address_space(3))) void lds_void_t;
typedef const __attribute__((address_space(1))) void gbl_void_t;

__device__ __forceinline__ ushort f32_to_bf16_rne(float x) {
    uint u = __float_as_uint(x);
    u = (u + 0x7FFFu + ((u >> 16) & 1u)) >> 16;
    return (ushort)u;
}
__device__ __forceinline__ float bf16_bits_to_f32(ushort b) {
    return __uint_as_float(((uint)b) << 16);
}

__device__ __forceinline__ float fast_tanh(float x) {
    float t = __expf(2.0f * x);
    float r = __builtin_amdgcn_rcpf(t + 1.0f);
    return fmaf(-2.0f, r, 1.0f);
}

// split 8 f32 -> hi bf16x8 (round-half-up) + lo bf16x8 (exact residual)
__device__ __forceinline__ void split8(float4 a, float4 b, bf16x8& hi8, bf16x8& lo8) {
    float xs[8] = {a.x, a.y, a.z, a.w, b.x, b.y, b.z, b.w};
    union { uint w[4]; bf16x8 v; } H, L;
#pragma unroll
    for (int p = 0; p < 4; ++p) {
        float x0 = xs[2 * p], x1 = xs[2 * p + 1];
        uint r0 = __float_as_uint(x0) + 0x8000u;
        uint r1 = __float_as_uint(x1) + 0x8000u;
        H.w[p] = __builtin_amdgcn_perm(r1, r0, 0x07060302u);
        float rem0 = x0 - __uint_as_float(r0 & 0xFFFF0000u);
        float rem1 = x1 - __uint_as_float(r1 & 0xFFFF0000u);
        L.w[p] = __builtin_amdgcn_perm(__float_as_uint(rem1), __float_as_uint(rem0), 0x07060302u);
    }
    hi8 = H.v;
    lo8 = L.v;
}

// -----------------------------------------------------------------------------
// Kernel 0: pre-swizzled W image, 4 chunks of 32KB (verified 0-conflict layout).
// Byte addr = ph*32768 + p*16384 + r*128 + sp*16, sp = s^(r&7). Chunks {0,1} =
// K-half 0, {2,3} = K-half 1, so a 64KB linear copy stages one K-half.
// -----------------------------------------------------------------------------
__global__ __launch_bounds__(256) void convert_W_kernel(
    const float* __restrict__ W, ushort* __restrict__ Wimg)
{
    const int c   = blockIdx.x * 256 + threadIdx.x;
    const int ph  = c >> 11;
    const int p   = (c >> 10) & 1;
    const int r   = (c >> 3) & 127;
    const int sp  = c & 7;
    const int s   = sp ^ (r & 7);
    const float* src = W + (size_t)r * D_ + ph * 64 + s * 8;

    union { ushort us[8]; float4 v; } out;
#pragma unroll
    for (int i = 0; i < 8; ++i) {
        float x = src[i];
        ushort hb = f32_to_bf16_rne(x);
        out.us[i] = p ? f32_to_bf16_rne(x - bf16_bits_to_f32(hb)) : hb;
    }
    *reinterpret_cast<float4*>(Wimg + (size_t)c * 8) = out.v;
}

// -----------------------------------------------------------------------------
// Kernel 1: fused score + flash pool, h read from HBM ONCE.
// R14 bug fixed: W re-stage boundary is now
//   lgkmcnt(0) -> s_barrier -> WSTAGE -> vmcnt(0) -> s_barrier
// (second barrier ensures ALL waves' slices landed, since each wave only
// waits its own vmcnt - the R14 race read other waves' unlanded W).
// - h pipe (R13-proven): 2x16KB LDS, global_load_lds, counted vmcnt(2).
// - bf16-hi h tile stashed to wave-private LDS each step; pool reads LDS ->
//   no second global h stream. Epilogue has NO vmem.
// Block = 8 waves x 16 rows x 4 groups = 512 rows; grid 256 (1 block/CU).
// LDS = 64K W + 32K pipe + 64K bf16 = 160KB exactly.
// -----------------------------------------------------------------------------
__global__ __launch_bounds__(512, 2) void score_pool_kernel(
    const float* __restrict__ h, const ushort* __restrict__ Wimg,
    const float* __restrict__ bw, const float* __restrict__ uw,
    float* __restrict__ part, float2* __restrict__ stats)
{
    __shared__ char smem[163840];
    char* wlds = smem;           // 64 KB: current W K-half (2 chunks of 32KB)
    char* ht   = smem + 65536;   // 32 KB: h pipe (2 x 16KB)
    char* hb16 = smem + 98304;   // 64 KB: bf16 h of current group (8KB/wave)

    const int tid  = threadIdx.x;
    const int w    = tid >> 6;
    const int lane = tid & 63;
    const int l15  = lane & 15;
    const int l4   = lane >> 4;
    const int blk  = blockIdx.x;
    const size_t blkrow = (size_t)blk * 512;

    float bwv[8], uwv[8];
#pragma unroll
    for (int j = 0; j < 8; ++j) { bwv[j] = bw[j * 16 + l15]; uwv[j] = uw[j * 16 + l15]; }
    __builtin_amdgcn_sched_barrier(0);

#define WSTAGE(hf)                                                             \
    {                                                                          \
        _Pragma("unroll")                                                      \
        for (int i = 0; i < 8; ++i)                                            \
            __builtin_amdgcn_global_load_lds(                                  \
                (gbl_void_t*)((const char*)Wimg + (hf) * 65536 + i * 8192 + tid * 16), \
                (lds_void_t*)(wlds + i * 8192 + w * 1024), 16, 0, 0);          \
    }

    // step s: g=s>>3, hf=(s>>2)&1, kkl=s&3. Stage = 16 rows x 32 f32 / wave.
#define HSTAGE(s2, buf)                                                         \
    {                                                                           \
        const int g_ = (s2) >> 3, hf_ = ((s2) >> 2) & 1, kk_ = (s2) & 3;        \
        const float* s0_ = h + (blkrow + g_ * 128 + (size_t)w * 16 + l15) * D_  \
                             + hf_ * 128 + kk_ * 32 + l4 * 4;                   \
        char* d_ = ht + (buf) * 16384 + w * 2048;                               \
        __builtin_amdgcn_global_load_lds((gbl_void_t*)(s0_),      (lds_void_t*)(d_),        16, 0, 0); \
        __builtin_amdgcn_global_load_lds((gbl_void_t*)(s0_ + 16), (lds_void_t*)(d_ + 1024), 16, 0, 0); \
    }

    // ---- prologue: W half0 + h stages 0,1; wait own W (h stays in flight);
    //      barrier-exit => ALL waves' W landed (each waited before barrier) ----
    WSTAGE(0);
    HSTAGE(0, 0);
    HSTAGE(1, 1);
    asm volatile("s_waitcnt vmcnt(4)" ::: "memory");
    __builtin_amdgcn_sched_barrier(0);
    __builtin_amdgcn_s_barrier();
    __builtin_amdgcn_sched_barrier(0);

    // per-lane pipe read offsets (R13-proven geometry)
    const int reg0 = (l4 >> 1) * 1024;
    const int rd0  = w * 2048 + reg0 + (((l4 * 2)     & 3) * 16 + l15) * 16;
    const int rd1  = w * 2048 + reg0 + (((l4 * 2 + 1) & 3) * 16 + l15) * 16;

    f32x4 acc[8];
#pragma unroll
    for (int j = 0; j < 8; ++j)
#pragma unroll
        for (int r = 0; r < 4; ++r) acc[j][r] = 0.f;

    float4 pacc[4];
    float  m_arr[4], s_arr[4];

#pragma unroll
    for (int s = 0; s < 32; ++s) {
        const int g   = s >> 3;
        const int hf  = (s >> 2) & 1;
        const int kkl = s & 3;
        const int buf = s & 1;

        if ((s & 3) == 0 && s > 0) {
            // W K-half boundary (RACE-FIXED protocol):
            asm volatile("s_waitcnt lgkmcnt(0)" ::: "memory");
            __builtin_amdgcn_sched_barrier(0);
            __builtin_amdgcn_s_barrier();            // old half no longer read
            __builtin_amdgcn_sched_barrier(0);
            WSTAGE(hf);
            asm volatile("s_waitcnt vmcnt(0)" ::: "memory");  // own slice landed
            __builtin_amdgcn_sched_barrier(0);
            __builtin_amdgcn_s_barrier();            // ALL slices landed
            __builtin_amdgcn_sched_barrier(0);
        } else if (s == 31) {
            asm volatile("s_waitcnt vmcnt(0)" ::: "memory");
        } else {
            asm volatile("s_waitcnt vmcnt(2)" ::: "memory");
        }
        __builtin_amdgcn_sched_barrier(0);

        float4 x0 = *reinterpret_cast<const float4*>(ht + buf * 16384 + rd0);
        float4 x1 = *reinterpret_cast<const float4*>(ht + buf * 16384 + rd1);
        asm volatile("s_waitcnt lgkmcnt(0)" ::: "memory");
        __builtin_amdgcn_sched_barrier(0);
        if (s + 2 < 32) HSTAGE(s + 2, buf);   // safe: reads of this buf retired

        bf16x8 ahi, alo;
        split8(x0, x1, ahi, alo);

        // stash bf16-hi tile for the pool (wave-private, swizzled slots)
        const int hslot = hf * 16 + kkl * 4 + l4;
        *reinterpret_cast<bf16x8*>(
            hb16 + w * 8192 + l15 * 512 + ((hslot ^ (l15 & 7)) << 4)) = ahi;

        const int chunk = kkl >> 1;
        const int slot  = (kkl & 1) * 4 + l4;
#pragma unroll
        for (int j = 0; j < 8; ++j) {
            const int row = j * 16 + l15;
            const int off = chunk * 32768 + row * 128 + ((slot ^ (row & 7)) << 4);
            bf16x8 wh = *reinterpret_cast<const bf16x8*>(wlds + off);
            bf16x8 wl = *reinterpret_cast<const bf16x8*>(wlds + 16384 + off);
            acc[j] = __builtin_amdgcn_mfma_f32_16x16x32_bf16(ahi, wh, acc[j], 0, 0, 0);
            acc[j] = __builtin_amdgcn_mfma_f32_16x16x32_bf16(alo, wh, acc[j], 0, 0, 0);
            acc[j] = __builtin_amdgcn_mfma_f32_16x16x32_bf16(ahi, wl, acc[j], 0, 0, 0);
        }

        if ((s & 7) == 7) {
            // ---- wave-local epilogue for group g (NO vmem) ----
            float rsum[4] = {0.f, 0.f, 0.f, 0.f};
#pragma unroll
            for (int j = 0; j < 8; ++j)
#pragma unroll
                for (int r = 0; r < 4; ++r) {
                    rsum[r] = fmaf(fast_tanh(acc[j][r] + bwv[j]), uwv[j], rsum[r]);
                    acc[j][r] = 0.f;
                }
#pragma unroll
            for (int r = 0; r < 4; ++r) {
#pragma unroll
                for (int m = 1; m < 16; m <<= 1)
                    rsum[r] += __shfl_xor(rsum[r], m, 64);
            }
            float sc16[16];
#pragma unroll
            for (int rr = 0; rr < 16; ++rr)
                sc16[rr] = __shfl(rsum[rr & 3], (rr >> 2) << 4, 64);

            float m_w = sc16[0];
#pragma unroll
            for (int rr = 1; rr < 16; ++rr) m_w = fmaxf(m_w, sc16[rr]);
            float e16[16], s_w = 0.f;
#pragma unroll
            for (int rr = 0; rr < 16; ++rr) { e16[rr] = __expf(sc16[rr] - m_w); s_w += e16[rr]; }

            // pool this wave's 16 rows from the LDS bf16 stash
            const int rslot = lane >> 1;
            const int sub   = (lane & 1) * 8;
            float4 pg = {0.f, 0.f, 0.f, 0.f};
#pragma unroll
            for (int r = 0; r < 16; ++r) {
                const ushort4 hv = *reinterpret_cast<const ushort4*>(
                    hb16 + w * 8192 + r * 512 + ((rslot ^ (r & 7)) << 4) + sub);
                pg.x = fmaf(e16[r], bf16_bits_to_f32(hv.x), pg.x);
                pg.y = fmaf(e16[r], bf16_bits_to_f32(hv.y), pg.y);
                pg.z = fmaf(e16[r], bf16_bits_to_f32(hv.z), pg.z);
                pg.w = fmaf(e16[r], bf16_bits_to_f32(hv.w), pg.w);
            }
            pacc[g]  = pg;
            m_arr[g] = m_w;
            s_arr[g] = s_w;
        }
    }
#undef HSTAGE
#undef WSTAGE

    // ---- block flash merge over 32 chunks (reuse dead LDS) ----
    float*  Pl  = (float*)smem;            // 32 KB
    float2* mst = (float2*)(smem + 32768); // 256 B
    __syncthreads();
#pragma unroll
    for (int g = 0; g < 4; ++g) {
        const int cid = g * 8 + w;
        *reinterpret_cast<float4*>(Pl + cid * 256 + lane * 4) = pacc[g];
        if (lane == 0) mst[cid] = make_float2(m_arr[g], s_arr[g]);
    }
    __syncthreads();
    if (tid < 256) {
        float M = -3.0e38f;
#pragma unroll
        for (int c = 0; c < 32; ++c) M = fmaxf(M, mst[c].x);
        float wc[32], S = 0.f;
#pragma unroll
        for (int c = 0; c < 32; ++c) {
            wc[c] = __expf(mst[c].x - M);
            S = fmaf(wc[c], mst[c].y, S);
        }
        float p = 0.f;
#pragma unroll
        for (int c = 0; c < 32; ++c) p = fmaf(wc[c], Pl[c * 256 + tid], p);
        part[(size_t)blk * 256 + tid] = p;
        if (tid == 0) stats[blk] = make_float2(M, S);
    }
}

// -----------------------------------------------------------------------------
// Kernel 2: per-batch flash combine over 8 block-partials.
// -----------------------------------------------------------------------------
__global__ __launch_bounds__(256) void combine_kernel(
    const float* __restrict__ part, const float2* __restrict__ stats,
    float* __restrict__ out)
{
    const int b = blockIdx.x;
    const int t = threadIdx.x;

    float m8[8], s8[8];
    float Mg = -3.0e38f;
#pragma unroll
    for (int c = 0; c < 8; ++c) {
        float2 st = stats[b * 8 + c];
        m8[c] = st.x; s8[c] = st.y;
        Mg = fmaxf(Mg, st.x);
    }
    float wc[8], S = 0.f;
#pragma unroll
    for (int c = 0; c < 8; ++c) {
        wc[c] = __expf(m8[c] - Mg);
        S = fmaf(wc[c], s8[c], S);
    }
    const float invS = 1.0f / S;

    float acc = 0.f;
#pragma unroll
    for (int c = 0; c < 8; ++c)
        acc = fmaf(wc[c], part[((size_t)b * 8 + c) * D_ + t], acc);
    out[b * D_ + t] = acc * invS;
}

extern "C" void kernel_launch(void* const* d_in, const int* in_sizes, int n_in,
                              void* d_out, int out_size, void* d_ws, size_t ws_size,
                              hipStream_t stream) {
    const float* h  = (const float*)d_in[0];
    const float* W  = (const float*)d_in[1];
    const float* bw = (const float*)d_in[2];
    const float* uw = (const float*)d_in[3];
    float* out = (float*)d_out;

    ushort* Wimg  = (ushort*)d_ws;                          // 128 KB
    float*  part  = (float*)(Wimg + (size_t)65536);         // 256*256*4 = 256 KB
    float2* stats = (float2*)(part + (size_t)256 * D_);     // 2 KB

    convert_W_kernel<<<dim3(32), 256, 0, stream>>>(W, Wimg);
    score_pool_kernel<<<dim3(256), 512, 0, stream>>>(h, Wimg, bw, uw, part, stats);
    combine_kernel<<<dim3(B_), 256, 0, stream>>>(part, stats, out);
}

// Round 16
// 47.580 us; speedup vs baseline: 1.1677x; 1.1677x over previous
//
#include <hip/hip_runtime.h>

#define B_ 32
#define T_ 4096
#define D_ 256
#define A_ 128

typedef __attribute__((ext_vector_type(8))) short bf16x8;
typedef __attribute__((ext_vector_type(4))) float f32x4;
typedef __attribute__((address_space(3))) void lds_void_t;
typedef const __attribute__((address_space(1))) void gbl_void_t;

__device__ __forceinline__ float bf16_bits_to_f32(ushort b) {
    return __uint_as_float(((uint)b) << 16);
}

__device__ __forceinline__ float fast_tanh(float x) {
    float t = __expf(2.0f * x);
    float r = __builtin_amdgcn_rcpf(t + 1.0f);
    return fmaf(-2.0f, r, 1.0f);
}

// split 8 f32 -> hi bf16x8 (round-half-up) + lo bf16x8 (exact residual)
__device__ __forceinline__ void split8(float4 a, float4 b, bf16x8& hi8, bf16x8& lo8) {
    float xs[8] = {a.x, a.y, a.z, a.w, b.x, b.y, b.z, b.w};
    union { uint w[4]; bf16x8 v; } H, L;
#pragma unroll
    for (int p = 0; p < 4; ++p) {
        float x0 = xs[2 * p], x1 = xs[2 * p + 1];
        uint r0 = __float_as_uint(x0) + 0x8000u;
        uint r1 = __float_as_uint(x1) + 0x8000u;
        H.w[p] = __builtin_amdgcn_perm(r1, r0, 0x07060302u);
        float rem0 = x0 - __uint_as_float(r0 & 0xFFFF0000u);
        float rem1 = x1 - __uint_as_float(r1 & 0xFFFF0000u);
        L.w[p] = __builtin_amdgcn_perm(__float_as_uint(rem1), __float_as_uint(rem0), 0x07060302u);
    }
    hi8 = H.v;
    lo8 = L.v;
}

// -----------------------------------------------------------------------------
// Kernel 1 (R13 structure + fused W build): score (split-bf16 MFMA) +
// per-wave flash pool + block flash merge. Two kernels total.
// - Prologue: h stages 0,1 issued FIRST (land during W build); each block
//   builds the swizzled 128KB W image in LDS from W f32 directly (L2-hot,
//   replaces the convert kernel + its launch gap + the Wimg round-trip).
//   Image byte addr = ph*32768 + p*16384 + r*128 + sp*16, sp = s^(r&7),
//   holding plane p of W[r][ph*64 + s*8 .. +8)  (identical to R13's image).
// - K-loop (R13-proven, untouched): h pipelined through LDS via
//   global_load_lds, 2x16KB double-buffer, counted vmcnt(2), zero barriers.
// - Epilogue per group: wave-local flash softmax + pool via L2-hot re-read.
// Block = 8 waves x 16 rows x 4 groups = 512 rows; grid 256 (1 block/CU).
// -----------------------------------------------------------------------------
__global__ __launch_bounds__(512, 2) void score_pool_kernel(
    const float* __restrict__ h, const float* __restrict__ W,
    const float* __restrict__ bw, const float* __restrict__ uw,
    float* __restrict__ part, float2* __restrict__ stats)
{
    __shared__ char smem[163840];
    char* wlds = smem;            // 128 KB W image
    char* ht   = smem + 131072;   // 2 x 16 KB h pipe

    const int tid  = threadIdx.x;
    const int w    = tid >> 6;
    const int lane = tid & 63;
    const int l15  = lane & 15;
    const int l4   = lane >> 4;
    const int blk  = blockIdx.x;
    const size_t blkrow = (size_t)blk * 512;

    float bwv[8], uwv[8];
#pragma unroll
    for (int j = 0; j < 8; ++j) { bwv[j] = bw[j * 16 + l15]; uwv[j] = uw[j * 16 + l15]; }
    __builtin_amdgcn_sched_barrier(0);

    // h staging geometry (R13): wave slice = 16 rows x 32 f32 per stage.
    const float* hlane = h + (blkrow + (size_t)w * 16 + l15) * D_ + l4 * 4;

#define HSTAGE(s2, buf)                                                         \
    {                                                                           \
        const float* s0_ = hlane + (size_t)((s2) >> 3) * 128 * D_ + ((s2) & 7) * 32; \
        char* d_ = ht + (buf) * 16384 + w * 2048;                               \
        __builtin_amdgcn_global_load_lds((gbl_void_t*)(s0_),      (lds_void_t*)(d_),        16, 0, 0); \
        __builtin_amdgcn_global_load_lds((gbl_void_t*)(s0_ + 16), (lds_void_t*)(d_ + 1024), 16, 0, 0); \
    }

    // ---- prologue: h0/h1 first (oldest -> land during W build) ----
    HSTAGE(0, 0);
    HSTAGE(1, 1);
    __builtin_amdgcn_sched_barrier(0);

    // ---- fused W build: 4096 tuples (ph, r, sp); 8 per thread ----
#pragma unroll
    for (int i = 0; i < 8; ++i) {
        const int cc  = i * 512 + tid;        // 0..4095
        const int ph  = cc >> 10;
        const int rem = cc & 1023;
        const int r   = rem >> 3;
        const int sp  = rem & 7;
        const int sx  = sp ^ (r & 7);
        const float* src = W + (size_t)r * D_ + ph * 64 + sx * 8;
        float4 a = *reinterpret_cast<const float4*>(src);
        float4 b = *reinterpret_cast<const float4*>(src + 4);
        bf16x8 hi, lo;
        split8(a, b, hi, lo);
        const int base = ph * 32768 + r * 128 + sp * 16;
        *reinterpret_cast<bf16x8*>(wlds + base)         = hi;
        *reinterpret_cast<bf16x8*>(wlds + 16384 + base) = lo;
    }
    asm volatile("s_waitcnt lgkmcnt(0)" ::: "memory");
    __builtin_amdgcn_sched_barrier(0);
    __builtin_amdgcn_s_barrier();      // W image complete for all waves
    __builtin_amdgcn_sched_barrier(0);

    // per-lane pipe read offsets (R13-proven geometry)
    const int reg0 = (l4 >> 1) * 1024;
    const int rd0  = w * 2048 + reg0 + (((l4 * 2)     & 3) * 16 + l15) * 16;
    const int rd1  = w * 2048 + reg0 + (((l4 * 2 + 1) & 3) * 16 + l15) * 16;

    f32x4 acc[8];
#pragma unroll
    for (int j = 0; j < 8; ++j)
#pragma unroll
        for (int r = 0; r < 4; ++r) acc[j][r] = 0.f;

    float4 pacc[4];
    float  m_arr[4], s_arr[4];

#pragma unroll
    for (int s = 0; s < 32; ++s) {
        const int g   = s >> 3;
        const int kk  = s & 7;
        const int buf = s & 1;

        if (s == 31) { asm volatile("s_waitcnt vmcnt(0)" ::: "memory"); }
        else         { asm volatile("s_waitcnt vmcnt(2)" ::: "memory"); }
        __builtin_amdgcn_sched_barrier(0);

        float4 x0 = *reinterpret_cast<const float4*>(ht + buf * 16384 + rd0);
        float4 x1 = *reinterpret_cast<const float4*>(ht + buf * 16384 + rd1);
        asm volatile("s_waitcnt lgkmcnt(0)" ::: "memory");
        __builtin_amdgcn_sched_barrier(0);
        if (s + 2 < 32) HSTAGE(s + 2, buf);   // safe: reads of this buf retired

        bf16x8 ahi, alo;
        split8(x0, x1, ahi, alo);

        const int chunk = kk >> 1;
        const int slot  = (kk & 1) * 4 + l4;
#pragma unroll
        for (int j = 0; j < 8; ++j) {
            const int row = j * 16 + l15;
            const int off = chunk * 32768 + row * 128 + ((slot ^ (row & 7)) << 4);
            bf16x8 wh = *reinterpret_cast<const bf16x8*>(wlds + off);
            bf16x8 wl = *reinterpret_cast<const bf16x8*>(wlds + 16384 + off);
            acc[j] = __builtin_amdgcn_mfma_f32_16x16x32_bf16(ahi, wh, acc[j], 0, 0, 0);
            acc[j] = __builtin_amdgcn_mfma_f32_16x16x32_bf16(alo, wh, acc[j], 0, 0, 0);
            acc[j] = __builtin_amdgcn_mfma_f32_16x16x32_bf16(ahi, wl, acc[j], 0, 0, 0);
        }

        if (kk == 7) {
            // ---- wave-local epilogue for group g (R13-proven) ----
            float rsum[4] = {0.f, 0.f, 0.f, 0.f};
#pragma unroll
            for (int j = 0; j < 8; ++j)
#pragma unroll
                for (int r = 0; r < 4; ++r) {
                    rsum[r] = fmaf(fast_tanh(acc[j][r] + bwv[j]), uwv[j], rsum[r]);
                    acc[j][r] = 0.f;
                }
#pragma unroll
            for (int r = 0; r < 4; ++r) {
#pragma unroll
                for (int m = 1; m < 16; m <<= 1)
                    rsum[r] += __shfl_xor(rsum[r], m, 64);
            }
            float sc16[16];
#pragma unroll
            for (int rr = 0; rr < 16; ++rr)
                sc16[rr] = __shfl(rsum[rr & 3], (rr >> 2) << 4, 64);

            float m_w = sc16[0];
#pragma unroll
            for (int rr = 1; rr < 16; ++rr) m_w = fmaxf(m_w, sc16[rr]);
            float e16[16], s_w = 0.f;
#pragma unroll
            for (int rr = 0; rr < 16; ++rr) { e16[rr] = __expf(sc16[rr] - m_w); s_w += e16[rr]; }

            // pool this wave's 16 rows (L2-hot: just streamed through LDS)
            const float* hg = h + (blkrow + (size_t)g * 128 + w * 16) * D_ + lane * 4;
            float4 pg = {0.f, 0.f, 0.f, 0.f};
#pragma unroll
            for (int r = 0; r < 16; ++r) {
                float4 v = *reinterpret_cast<const float4*>(hg + (size_t)r * D_);
                pg.x = fmaf(e16[r], v.x, pg.x);
                pg.y = fmaf(e16[r], v.y, pg.y);
                pg.z = fmaf(e16[r], v.z, pg.z);
                pg.w = fmaf(e16[r], v.w, pg.w);
            }
            pacc[g]  = pg;
            m_arr[g] = m_w;
            s_arr[g] = s_w;

            asm volatile("s_waitcnt vmcnt(0)" ::: "memory");   // resync ledger
            __builtin_amdgcn_sched_barrier(0);
        }
    }
#undef HSTAGE

    // ---- block flash merge over 32 chunks (reuse dead LDS) ----
    float2* mst = (float2*)wlds;
    float*  Pl  = (float*)ht;
    __syncthreads();
#pragma unroll
    for (int g = 0; g < 4; ++g) {
        const int cid = g * 8 + w;
        *reinterpret_cast<float4*>(Pl + cid * 256 + lane * 4) = pacc[g];
        if (lane == 0) mst[cid] = make_float2(m_arr[g], s_arr[g]);
    }
    __syncthreads();
    if (tid < 256) {
        float M = -3.0e38f;
#pragma unroll
        for (int c = 0; c < 32; ++c) M = fmaxf(M, mst[c].x);
        float wc[32], S = 0.f;
#pragma unroll
        for (int c = 0; c < 32; ++c) {
            wc[c] = __expf(mst[c].x - M);
            S = fmaf(wc[c], mst[c].y, S);
        }
        float p = 0.f;
#pragma unroll
        for (int c = 0; c < 32; ++c) p = fmaf(wc[c], Pl[c * 256 + tid], p);
        part[(size_t)blk * 256 + tid] = p;
        if (tid == 0) stats[blk] = make_float2(M, S);
    }
}

// -----------------------------------------------------------------------------
// Kernel 2: per-batch flash combine over 8 block-partials.
// out[b][d] = sum_c exp(M_c-Mg)*P_c[d] / sum_c exp(M_c-Mg)*S_c.
// -----------------------------------------------------------------------------
__global__ __launch_bounds__(256) void combine_kernel(
    const float* __restrict__ part, const float2* __restrict__ stats,
    float* __restrict__ out)
{
    const int b = blockIdx.x;
    const int t = threadIdx.x;

    float m8[8], s8[8];
    float Mg = -3.0e38f;
#pragma unroll
    for (int c = 0; c < 8; ++c) {
        float2 st = stats[b * 8 + c];
        m8[c] = st.x; s8[c] = st.y;
        Mg = fmaxf(Mg, st.x);
    }
    float wc[8], S = 0.f;
#pragma unroll
    for (int c = 0; c < 8; ++c) {
        wc[c] = __expf(m8[c] - Mg);
        S = fmaf(wc[c], s8[c], S);
    }
    const float invS = 1.0f / S;

    float acc = 0.f;
#pragma unroll
    for (int c = 0; c < 8; ++c)
        acc = fmaf(wc[c], part[((size_t)b * 8 + c) * D_ + t], acc);
    out[b * D_ + t] = acc * invS;
}

extern "C" void kernel_launch(void* const* d_in, const int* in_sizes, int n_in,
                              void* d_out, int out_size, void* d_ws, size_t ws_size,
                              hipStream_t stream) {
    const float* h  = (const float*)d_in[0];
    const float* W  = (const float*)d_in[1];
    const float* bw = (const float*)d_in[2];
    const float* uw = (const float*)d_in[3];
    float* out = (float*)d_out;

    float*  part  = (float*)d_ws;                           // 256*256*4 = 256 KB
    float2* stats = (float2*)(part + (size_t)256 * D_);     // 2 KB

    score_pool_kernel<<<dim3(256), 512, 0, stream>>>(h, W, bw, uw, part, stats);
    combine_kernel<<<dim3(B_), 256, 0, stream>>>(part, stats, out);
}